// Round 6
// baseline (209.375 us; speedup 1.0000x reference)
//
#include <hip/hip_runtime.h>
#include <cmath>
#include <cstdint>

#define BATCH  256
#define TT     1024
#define FIN    16
#define LSZ    256
#define NBULK  64
#define NCOH   32
#define TC     16
#define NCHUNK (TT / TC)          // 64
#define YSS    336                // s_y row stride (bf16)

typedef __attribute__((ext_vector_type(8))) short short8;
typedef __attribute__((ext_vector_type(4))) float floatx4;

__device__ __forceinline__ unsigned short f2bf_rne(float f) {
    union { float f; unsigned int i; } v; v.f = f;
    unsigned int b = v.i;
    return (unsigned short)((b + 0x7FFFu + ((b >> 16) & 1u)) >> 16);
}
__device__ __forceinline__ unsigned int bfbits(float f) {  // round-half-up
    union { float f; unsigned int i; } v; v.f = f;
    return v.i + 0x8000u;
}

// Material constants (plane stress)
#define MC00   219.78021978021977f
#define MC01   65.93406593406593f
#define MC22   76.92307692307692f
#define MSY0   2.0f
#define AK     0.958466453674121406f  // 3G/(3G+H)
#define BK     0.041533546325878594f  // H/(3G+H)

// flag indices
#define F_HPROD  0
#define F_HCONS0 1
#define F_HCONS1 2
#define F_YPROD0 3
#define F_YPROD1 4
#define F_YCONS  5

__device__ __forceinline__ void flag_set(int* f, int v) {
    __hip_atomic_store(f, v, __ATOMIC_RELEASE, __HIP_MEMORY_SCOPE_WORKGROUP);
}
__device__ __forceinline__ void flag_wait(int* f, int target) {
    while (__hip_atomic_load(f, __ATOMIC_ACQUIRE, __HIP_MEMORY_SCOPE_WORKGROUP) < target) {
        __builtin_amdgcn_s_sleep(1);
    }
}

__global__ __launch_bounds__(256, 1)
void fused_mat_kernel(const float* __restrict__ x,
                      const float* __restrict__ w1,
                      const float* __restrict__ w2,
                      float* __restrict__ out)
{
    __shared__ __attribute__((aligned(16))) float          s_hb[2][TC][256];  // 32 KB
    __shared__ __attribute__((aligned(16))) float          s_hc[2][TC][64];   // 8 KB
    __shared__ __attribute__((aligned(16))) unsigned short s_y [2][TC][YSS];  // 21504 B
    __shared__ int s_flags[8];

    const int tid  = threadIdx.x;
    const int b    = blockIdx.x;
    const int lane = tid & 63;
    const int wv   = tid >> 6;
    const int m    = lane & 15;
    const int q    = lane >> 4;

    const size_t xrow = (size_t)b * TT;

    if (tid < 8) s_flags[tid] = 0;

    short8 w1f[16];
    short8 vf[10];

    if (wv == 2) {
        #pragma unroll
        for (int n = 0; n < 16; ++n) {
            #pragma unroll
            for (int j = 0; j < 8; ++j) {
                unsigned short v = 0;
                if (q < 2) v = f2bf_rne(w1[(n * 16 + m) * FIN + q * 8 + j]);
                w1f[n][j] = (short)v;
            }
        }
    } else if (wv == 3) {
        #pragma unroll
        for (int ks = 0; ks < 10; ++ks) {
            #pragma unroll
            for (int j = 0; j < 8; ++j) {
                const int p = ks * 32 + q * 8 + j;
                unsigned short v = 0;
                if (p < 256) {
                    const int comp = p & 3;
                    if (comp < 3) {
                        const int l = 3 * (p >> 2) + comp;
                        float xv = w2[m * LSZ + l];
                        float sp = fmaxf(xv, 0.0f) + log1pf(expf(-fabsf(xv)));
                        v = f2bf_rne(sp);
                    }
                } else {
                    const int l = p - 64;
                    float xv = w2[m * LSZ + l];
                    float sp = fmaxf(xv, 0.0f) + log1pf(expf(-fabsf(xv)));
                    v = f2bf_rne(sp);
                }
                vf[ks][j] = (short)v;
            }
        }
    }

    __syncthreads();   // flags initialized; the ONLY barrier

    if (wv == 0) {
        // ---------------- bulk J2: 64 chains ----------------
        float sg0 = 0.f, sg1 = 0.f, sg2 = 0.f, syv = MSY0;
        float ep0 = 0.f, ep1 = 0.f, ep2 = 0.f;
        for (int c = 0; c < NCHUNK; ++c) {
            flag_wait(&s_flags[F_HPROD], c + 1);
            const float* hb = &s_hb[c & 1][0][0];
            floatx4 ev[TC];
            #pragma unroll
            for (int t = 0; t < TC; ++t)
                ev[t] = *(const floatx4*)(hb + t * 256 + lane * 4);
            if (lane == 0) flag_set(&s_flags[F_HCONS0], c + 1);
            flag_wait(&s_flags[F_YCONS], c - 1);
            unsigned short* yb = &s_y[c & 1][0][0];
            #pragma unroll
            for (int t = 0; t < TC; ++t) {
                const float d0 = ev[t].x - ep0, d1 = ev[t].y - ep1, d2 = ev[t].z - ep2;
                ep0 = ev[t].x; ep1 = ev[t].y; ep2 = ev[t].z;
                const float dl0 = fmaf(MC01, d1, MC00 * d0);
                const float dl1 = fmaf(MC00, d1, MC01 * d0);
                const float dl2 = MC22 * d2;
                const float pre = AK * syv;
                const float t0 = sg0 + dl0, t1 = sg1 + dl1, t2 = sg2 + dl2;
                float qq = t0 * t0;
                qq = fmaf(-t0, t1, qq);
                qq = fmaf(t1, t1, qq);
                const float t2s = t2 * t2;
                qq = fmaf(3.0f, t2s, qq);
                qq = fmaxf(qq, 1e-12f);
                const float rs  = __builtin_amdgcn_rsqf(qq);
                const float seq = qq * rs;
                const float rr  = fminf(fmaf(pre, rs, BK), 1.0f);
                sg0 = rr * t0; sg1 = rr * t1; sg2 = rr * t2;
                syv = fmaf(BK, fmaxf(seq - syv, 0.0f), syv);
                uint2 pk;
                pk.x = (bfbits(sg0) >> 16) | (bfbits(sg1) & 0xFFFF0000u);
                pk.y = (bfbits(sg2) >> 16);
                *(uint2*)(yb + t * YSS + lane * 4) = pk;
            }
            if (lane == 0) flag_set(&s_flags[F_YPROD0], c + 1);
        }
    } else if (wv == 1) {
        // ---------------- cohesive: 32 chains ----------------
        float hist = 0.f;
        for (int c = 0; c < NCHUNK; ++c) {
            flag_wait(&s_flags[F_HPROD], c + 1);
            const float* hc = &s_hc[c & 1][0][0];
            float2 jv[TC];
            if (lane < NCOH) {
                #pragma unroll
                for (int t = 0; t < TC; ++t)
                    jv[t] = *(const float2*)(hc + t * 64 + 2 * lane);
            }
            if (lane == 0) flag_set(&s_flags[F_HCONS1], c + 1);
            flag_wait(&s_flags[F_YCONS], c - 1);
            if (lane < NCOH) {
                unsigned short* yb = &s_y[c & 1][0][0];
                #pragma unroll
                for (int t = 0; t < TC; ++t) {
                    const float dn = jv[t].x, ds = jv[t].y;
                    const float dnp = fmaxf(dn, 0.0f);
                    const float lam = sqrtf(fmaxf(fmaf(dnp, dnp, ds * ds), 1e-12f));
                    hist = fmaxf(hist, lam);
                    float dmg = (hist - 0.1f) * __builtin_amdgcn_rcpf(hist * 0.9f);
                    dmg = fminf(fmaxf(dmg, 0.0f), 1.0f);
                    const float om = 1.0f - dmg;
                    const float tn = 50.0f * dn * (dn > 0.0f ? om : 1.0f);
                    const float ts = om * 50.0f * ds;
                    unsigned int pk = (bfbits(tn) >> 16) | (bfbits(ts) & 0xFFFF0000u);
                    *(unsigned int*)(yb + t * YSS + 256 + 2 * lane) = pk;
                }
            }
            if (lane == 0) flag_set(&s_flags[F_YPROD1], c + 1);
        }
    } else if (wv == 2) {
        // ---------------- h-GEMM producer ----------------
        uint4 ra[2], rb[2];   // raw x bits, 2 chunks in flight
        #pragma unroll
        for (int s = 0; s < 2; ++s) {
            if (q < 2) {
                const float* xp = x + (xrow + s * TC + m) * FIN + q * 8;
                ra[s] = *(const uint4*)xp;
                rb[s] = *(const uint4*)(xp + 4);
            }
        }
        for (int c = 0; c < NCHUNK; ++c) {
            // convert chunk c (loaded >=1 chunk ago)
            short8 af;
            {
                const uint4 a = ra[c & 1], bb = rb[c & 1];
                const unsigned int w[8] = {a.x, a.y, a.z, a.w, bb.x, bb.y, bb.z, bb.w};
                #pragma unroll
                for (int j = 0; j < 8; ++j) {
                    unsigned short v = 0;
                    if (q < 2) {
                        union { unsigned int i; float f; } u; u.i = w[j];
                        v = f2bf_rne(u.f);
                    }
                    af[j] = (short)v;
                }
            }
            // issue load for chunk c+2 into the freed slot
            if (c + 2 < NCHUNK && q < 2) {
                const float* xp = x + (xrow + (c + 2) * TC + m) * FIN + q * 8;
                ra[c & 1] = *(const uint4*)xp;
                rb[c & 1] = *(const uint4*)(xp + 4);
            }
            if (c >= 2) {
                flag_wait(&s_flags[F_HCONS0], c - 1);
                flag_wait(&s_flags[F_HCONS1], c - 1);
            }
            float* hbw = &s_hb[c & 1][0][0];
            float* hcw = &s_hc[c & 1][0][0];
            #pragma unroll
            for (int n = 0; n < 16; ++n) {
                floatx4 acc = {0.f, 0.f, 0.f, 0.f};
                acc = __builtin_amdgcn_mfma_f32_16x16x32_bf16(af, w1f[n], acc, 0, 0, 0);
                const int col = n * 16 + m;
                if (n < 12) {
                    const int cc = col / 3, cm = col - cc * 3;
                    #pragma unroll
                    for (int r = 0; r < 4; ++r) hbw[(q * 4 + r) * 256 + cc * 4 + cm] = acc[r];
                } else {
                    #pragma unroll
                    for (int r = 0; r < 4; ++r) hcw[(q * 4 + r) * 64 + col - 192] = acc[r];
                }
            }
            if (lane == 0) flag_set(&s_flags[F_HPROD], c + 1);
        }
    } else {
        // ---------------- out-GEMM consumer ----------------
        for (int c = 0; c < NCHUNK; ++c) {
            flag_wait(&s_flags[F_YPROD0], c + 1);
            flag_wait(&s_flags[F_YPROD1], c + 1);
            const unsigned short* yb = &s_y[c & 1][0][0];
            floatx4 a0 = {0.f, 0.f, 0.f, 0.f};
            floatx4 a1 = {0.f, 0.f, 0.f, 0.f};
            #pragma unroll
            for (int ks = 0; ks < 5; ++ks) {
                const short8* yp = (const short8*)(yb + m * YSS + ks * 32 + q * 8);
                a0 = __builtin_amdgcn_mfma_f32_16x16x32_bf16(*yp, vf[ks], a0, 0, 0, 0);
            }
            #pragma unroll
            for (int ks = 5; ks < 10; ++ks) {
                const short8* yp = (const short8*)(yb + m * YSS + ks * 32 + q * 8);
                a1 = __builtin_amdgcn_mfma_f32_16x16x32_bf16(*yp, vf[ks], a1, 0, 0, 0);
            }
            if (lane == 0) flag_set(&s_flags[F_YCONS], c + 1);
            const int t0 = c * TC;
            #pragma unroll
            for (int r = 0; r < 4; ++r)
                out[(xrow + t0 + q * 4 + r) * FIN + m] = a0[r] + a1[r];
        }
    }
}

extern "C" void kernel_launch(void* const* d_in, const int* in_sizes, int n_in,
                              void* d_out, int out_size, void* d_ws, size_t ws_size,
                              hipStream_t stream) {
    const float* x  = (const float*)d_in[0];   // [256,1024,16] f32
    const float* w1 = (const float*)d_in[1];   // [256,16] f32
    const float* w2 = (const float*)d_in[2];   // [16,256] f32
    float* out = (float*)d_out;                // [256,1024,16] f32
    fused_mat_kernel<<<BATCH, 256, 0, stream>>>(x, w1, w2, out);
}

// Round 7
// 174.594 us; speedup vs baseline: 1.1992x; 1.1992x over previous
//
#include <hip/hip_runtime.h>
#include <cmath>
#include <cstdint>

#define BATCH  256
#define TT     1024
#define FIN    16
#define LSZ    256
#define NBULK  64
#define NCOH   32
#define TC     32
#define NCHUNK (TT / TC)          // 32
#define HBS    260                // s_hb row stride (floats): rows 4 banks apart
#define HCS    68                 // s_hc row stride (floats): rows 4 banks apart
#define YSS    336                // s_y row stride (bf16): 672B rows, 16B aligned

typedef __attribute__((ext_vector_type(8))) short short8;
typedef __attribute__((ext_vector_type(4))) float floatx4;

__device__ __forceinline__ unsigned short f2bf_rne(float f) {
    union { float f; unsigned int i; } v; v.f = f;
    unsigned int b = v.i;
    return (unsigned short)((b + 0x7FFFu + ((b >> 16) & 1u)) >> 16);
}
__device__ __forceinline__ unsigned int bfbits(float f) {  // round-half-up
    union { float f; unsigned int i; } v; v.f = f;
    return v.i + 0x8000u;
}

// Material constants (plane stress)
#define MC00   219.78021978021977f
#define MC01   65.93406593406593f
#define MC22   76.92307692307692f
#define MSY0   2.0f
#define AK     0.958466453674121406f  // 3G/(3G+H)
#define BK     0.041533546325878594f  // H/(3G+H)

__global__ __launch_bounds__(256, 1)
void fused_mat_kernel(const float* __restrict__ x,
                      const float* __restrict__ w1,
                      const float* __restrict__ w2,
                      float* __restrict__ out)
{
    __shared__ __attribute__((aligned(16))) float          s_hb[2][TC][HBS];  // 66560 B
    __shared__ __attribute__((aligned(16))) float          s_hc[2][TC][HCS];  // 17408 B
    __shared__ __attribute__((aligned(16))) unsigned short s_y [2][TC][YSS];  // 43008 B

    const int tid  = threadIdx.x;
    const int b    = blockIdx.x;
    const int lane = tid & 63;
    const int wv   = tid >> 6;    // 0: bulk, 1: cohesive, 2: h-GEMM, 3: out-GEMM
    const int m    = lane & 15;
    const int q    = lane >> 4;

    const size_t xrow = (size_t)b * TT;

    short8 w1f[16];   // wave 2
    short8 vf[10];    // wave 3 (permuted-k layout)
    uint4  rxa[2], rxb[2];  // wave 2: raw x bits for next chunk, per M-tile

    if (wv == 2) {
        #pragma unroll
        for (int n = 0; n < 16; ++n) {
            #pragma unroll
            for (int j = 0; j < 8; ++j) {
                unsigned short v = 0;
                if (q < 2) v = f2bf_rne(w1[(n * 16 + m) * FIN + q * 8 + j]);
                w1f[n][j] = (short)v;
            }
        }
        // prologue: produce chunk 0 (2 M-tiles) into buffer 0
        #pragma unroll
        for (int mt = 0; mt < 2; ++mt) {
            short8 a0;
            #pragma unroll
            for (int j = 0; j < 8; ++j) {
                unsigned short v = 0;
                if (q < 2) v = f2bf_rne(x[(xrow + mt * 16 + m) * FIN + q * 8 + j]);
                a0[j] = (short)v;
            }
            #pragma unroll
            for (int n = 0; n < 16; ++n) {
                floatx4 acc = {0.f, 0.f, 0.f, 0.f};
                acc = __builtin_amdgcn_mfma_f32_16x16x32_bf16(a0, w1f[n], acc, 0, 0, 0);
                const int col = n * 16 + m;
                if (n < 12) {
                    const int cc = col / 3, cm = col - cc * 3;
                    #pragma unroll
                    for (int r = 0; r < 4; ++r)
                        s_hb[0][mt * 16 + q * 4 + r][cc * 4 + cm] = acc[r];
                } else {
                    #pragma unroll
                    for (int r = 0; r < 4; ++r)
                        s_hc[0][mt * 16 + q * 4 + r][col - 192] = acc[r];
                }
            }
        }
        // prefetch raw x for chunk 1
        if (q < 2) {
            #pragma unroll
            for (int mt = 0; mt < 2; ++mt) {
                const float* xp = x + (xrow + TC + mt * 16 + m) * FIN + q * 8;
                rxa[mt] = *(const uint4*)xp;
                rxb[mt] = *(const uint4*)(xp + 4);
            }
        }
    } else if (wv == 3) {
        #pragma unroll
        for (int ks = 0; ks < 10; ++ks) {
            #pragma unroll
            for (int j = 0; j < 8; ++j) {
                const int p = ks * 32 + q * 8 + j;
                unsigned short v = 0;
                if (p < 256) {
                    const int comp = p & 3;
                    if (comp < 3) {
                        const int l = 3 * (p >> 2) + comp;
                        float xv = w2[m * LSZ + l];
                        float sp = fmaxf(xv, 0.0f) + log1pf(expf(-fabsf(xv)));
                        v = f2bf_rne(sp);
                    }
                } else {
                    const int l = p - 64;  // 192 + (p-256)
                    float xv = w2[m * LSZ + l];
                    float sp = fmaxf(xv, 0.0f) + log1pf(expf(-fabsf(xv)));
                    v = f2bf_rne(sp);
                }
                vf[ks][j] = (short)v;
            }
        }
    }

    // material state
    float sg0 = 0.f, sg1 = 0.f, sg2 = 0.f, syv = MSY0;
    float ep0 = 0.f, ep1 = 0.f, ep2 = 0.f;   // wave 0
    float hist = 0.f;                         // wave 1

    __syncthreads();   // chunk 0 visible

    for (int i = 0; i <= NCHUNK; ++i) {
        if (wv == 0) {
            if (i < NCHUNK) {
                const float* hb = &s_hb[i & 1][0][0];
                // hoist ALL chunk loads: chain starts when ev[0] lands, rest stream in
                floatx4 ev[TC];
                #pragma unroll
                for (int t = 0; t < TC; ++t)
                    ev[t] = *(const floatx4*)(hb + t * HBS + lane * 4);
                unsigned short* yb = &s_y[i & 1][0][0];
                #pragma unroll
                for (int t = 0; t < TC; ++t) {
                    const float e0 = ev[t].x, e1 = ev[t].y, e2 = ev[t].z;
                    const float d0 = e0 - ep0, d1 = e1 - ep1, d2 = e2 - ep2;
                    ep0 = e0; ep1 = e1; ep2 = e2;
                    const float dl0 = fmaf(MC01, d1, MC00 * d0);
                    const float dl1 = fmaf(MC00, d1, MC01 * d0);
                    const float dl2 = MC22 * d2;
                    const float pre = AK * syv;
                    const float t0 = sg0 + dl0, t1 = sg1 + dl1, t2 = sg2 + dl2;
                    const float a1 = t0 * (t0 - t1);                   // tree half 1
                    const float b1 = fmaf(t1, t1, 3.0f * (t2 * t2));   // tree half 2
                    const float qq = fmaxf(a1 + b1, 1e-12f);
                    const float rs  = __builtin_amdgcn_rsqf(qq);
                    const float seq = qq * rs;
                    const float rr  = fminf(fmaf(pre, rs, BK), 1.0f);
                    sg0 = rr * t0; sg1 = rr * t1; sg2 = rr * t2;
                    syv = fmaf(BK, fmaxf(seq - syv, 0.0f), syv);
                    uint2 pk;
                    pk.x = (bfbits(sg0) >> 16) | (bfbits(sg1) & 0xFFFF0000u);
                    pk.y = (bfbits(sg2) >> 16);
                    *(uint2*)(yb + t * YSS + lane * 4) = pk;
                }
            }
        } else if (wv == 1) {
            if (i < NCHUNK && lane < NCOH) {
                const float* hc = &s_hc[i & 1][0][0];
                float2 jv[TC];
                #pragma unroll
                for (int t = 0; t < TC; ++t)
                    jv[t] = *(const float2*)(hc + t * HCS + 2 * lane);
                unsigned short* yb = &s_y[i & 1][0][0];
                #pragma unroll
                for (int t = 0; t < TC; ++t) {
                    const float dn = jv[t].x, ds = jv[t].y;
                    const float dnp = fmaxf(dn, 0.0f);
                    const float lam = sqrtf(fmaxf(fmaf(dnp, dnp, ds * ds), 1e-12f));
                    hist = fmaxf(hist, lam);
                    float dmg = (hist - 0.1f) * __builtin_amdgcn_rcpf(hist * 0.9f);
                    dmg = fminf(fmaxf(dmg, 0.0f), 1.0f);
                    const float om = 1.0f - dmg;
                    const float tn = 50.0f * dn * (dn > 0.0f ? om : 1.0f);
                    const float ts = om * 50.0f * ds;
                    unsigned int pk = (bfbits(tn) >> 16) | (bfbits(ts) & 0xFFFF0000u);
                    *(unsigned int*)(yb + t * YSS + 256 + 2 * lane) = pk;
                }
            }
        } else if (wv == 2) {
            if (i + 1 < NCHUNK) {
                // convert prefetched raw x -> A-fragments for chunk i+1
                short8 af[2];
                #pragma unroll
                for (int mt = 0; mt < 2; ++mt) {
                    const unsigned int w[8] = {rxa[mt].x, rxa[mt].y, rxa[mt].z, rxa[mt].w,
                                               rxb[mt].x, rxb[mt].y, rxb[mt].z, rxb[mt].w};
                    #pragma unroll
                    for (int j = 0; j < 8; ++j) {
                        unsigned short v = 0;
                        if (q < 2) {
                            union { unsigned int i; float f; } u; u.i = w[j];
                            v = f2bf_rne(u.f);
                        }
                        af[mt][j] = (short)v;
                    }
                }
                // issue raw loads for chunk i+2 (consumed next interval)
                if (i + 2 < NCHUNK && q < 2) {
                    #pragma unroll
                    for (int mt = 0; mt < 2; ++mt) {
                        const float* xp = x + (xrow + (i + 2) * TC + mt * 16 + m) * FIN + q * 8;
                        rxa[mt] = *(const uint4*)xp;
                        rxb[mt] = *(const uint4*)(xp + 4);
                    }
                }
                float* hbw = &s_hb[(i + 1) & 1][0][0];
                float* hcw = &s_hc[(i + 1) & 1][0][0];
                #pragma unroll
                for (int mt = 0; mt < 2; ++mt) {
                    #pragma unroll
                    for (int n = 0; n < 16; ++n) {
                        floatx4 acc = {0.f, 0.f, 0.f, 0.f};
                        acc = __builtin_amdgcn_mfma_f32_16x16x32_bf16(af[mt], w1f[n], acc, 0, 0, 0);
                        const int col = n * 16 + m;
                        if (n < 12) {
                            const int cc = col / 3, cm = col - cc * 3;
                            #pragma unroll
                            for (int r = 0; r < 4; ++r)
                                hbw[(mt * 16 + q * 4 + r) * HBS + cc * 4 + cm] = acc[r];
                        } else {
                            #pragma unroll
                            for (int r = 0; r < 4; ++r)
                                hcw[(mt * 16 + q * 4 + r) * HCS + col - 192] = acc[r];
                        }
                    }
                }
            }
        } else {
            if (i >= 1) {
                const int t0 = (i - 1) * TC;
                const unsigned short* yb = &s_y[(i - 1) & 1][0][0];
                #pragma unroll
                for (int mt = 0; mt < 2; ++mt) {
                    floatx4 a0 = {0.f, 0.f, 0.f, 0.f};
                    floatx4 a1 = {0.f, 0.f, 0.f, 0.f};
                    #pragma unroll
                    for (int ks = 0; ks < 5; ++ks) {
                        const short8* yp = (const short8*)(yb + (mt * 16 + m) * YSS + ks * 32 + q * 8);
                        a0 = __builtin_amdgcn_mfma_f32_16x16x32_bf16(*yp, vf[ks], a0, 0, 0, 0);
                    }
                    #pragma unroll
                    for (int ks = 5; ks < 10; ++ks) {
                        const short8* yp = (const short8*)(yb + (mt * 16 + m) * YSS + ks * 32 + q * 8);
                        a1 = __builtin_amdgcn_mfma_f32_16x16x32_bf16(*yp, vf[ks], a1, 0, 0, 0);
                    }
                    #pragma unroll
                    for (int r = 0; r < 4; ++r)
                        out[(xrow + t0 + mt * 16 + q * 4 + r) * FIN + m] = a0[r] + a1[r];
                }
            }
        }
        __syncthreads();
    }
}

extern "C" void kernel_launch(void* const* d_in, const int* in_sizes, int n_in,
                              void* d_out, int out_size, void* d_ws, size_t ws_size,
                              hipStream_t stream) {
    const float* x  = (const float*)d_in[0];   // [256,1024,16] f32
    const float* w1 = (const float*)d_in[1];   // [256,16] f32
    const float* w2 = (const float*)d_in[2];   // [16,256] f32
    float* out = (float*)d_out;                // [256,1024,16] f32
    fused_mat_kernel<<<BATCH, 256, 0, stream>>>(x, w1, w2, out);
}